// Round 4
// baseline (240.647 us; speedup 1.0000x reference)
//
#include <hip/hip_runtime.h>
#include <math.h>

// out[b, l, d] = x[b, l, d] + pe[l, d]
// pe[l, 0:128]   : interleaved sin/cos of row * freq_m   (m = 0..63)
// pe[l, 128:256] : interleaved sin/cos of col * freq_m
// freq_m = exp(-m * ln(10000)/64),  l = row * w + col,  d_model = 256
//
// Work decomposition: one unit = one (l, j) pair (j = float4 index within d).
// Each unit computes the PE float4 ONCE, then loops over all b batch images
// (stride L*64 float4s), amortizing divisions + transcendentals by the batch
// count and giving nb independent load->add->store streams for ILP.
//
// NOTE: harness's out_size is in FLOAT ELEMENTS, not bytes (round-0 kernel
// with n4 = out_size/4 verified; out_size/16 under-covered the batch -> fail).

// Native clang vector type: required by __builtin_nontemporal_load/store
// (HIP's float4 is a class and is rejected by the builtin).
typedef float f32x4 __attribute__((ext_vector_type(4)));

__global__ __launch_bounds__(256) void pe_add_kernel(
    const float* __restrict__ x,
    const int* __restrict__ hp,
    const int* __restrict__ wp,
    float* __restrict__ out,
    unsigned int n4)   // total number of float4 elements (b * L * 64)
{
    const unsigned int ww = (unsigned int)(*wp);
    const unsigned int hh = (unsigned int)(*hp);
    const unsigned int L  = hh * ww;
    const unsigned int span = L << 6;            // float4s per batch image
    if (span == 0u) return;
    const unsigned int nb = n4 / span;           // batch count

    // power-of-two fast path for the row/col split (w=128 in the bench)
    const bool wpow2 = (ww & (ww - 1u)) == 0u;
    const unsigned int wshift = (unsigned int)__builtin_ctz(ww);
    const unsigned int wmask  = ww - 1u;

    const float cstep = 0.14391156831212787f;    // ln(10000)/64

    const unsigned int stride = gridDim.x * blockDim.x;
    for (unsigned int u = blockIdx.x * blockDim.x + threadIdx.x;
         u < span; u += stride) {

        const unsigned int j = u & 63u;          // float4 index within d (0..63)
        const unsigned int l = u >> 6;           // spatial position

        unsigned int row, col;
        if (wpow2) { row = l >> wshift; col = l & wmask; }
        else       { row = l / ww;      col = l - row * ww; }

        const unsigned int d0 = j << 2;          // starting channel (0..252)
        const unsigned int dd = d0 & 127u;       // offset within row/col half
        const float pos = (float)((d0 < 128u) ? row : col);

        const unsigned int m0 = dd >> 1;         // frequency index of first pair
        const float f0 = __expf(-(float)m0 * cstep);
        const float f1 = __expf(-(float)(m0 + 1u) * cstep);

        float s0, c0, s1, c1;
        __sincosf(pos * f0, &s0, &c0);
        __sincosf(pos * f1, &s1, &c1);

        const f32x4* xp = reinterpret_cast<const f32x4*>(x) + u;
        f32x4*       op = reinterpret_cast<f32x4*>(out) + u;

        const f32x4 pe = { s0, c0, s1, c1 };

        #pragma unroll 8
        for (unsigned int b = 0; b < nb; ++b) {
            f32x4 xv = __builtin_nontemporal_load(xp);
            f32x4 ov = xv + pe;
            __builtin_nontemporal_store(ov, op);
            xp += span;
            op += span;
        }
    }
}

extern "C" void kernel_launch(void* const* d_in, const int* in_sizes, int n_in,
                              void* d_out, int out_size, void* d_ws, size_t ws_size,
                              hipStream_t stream) {
    const float* x = (const float*)d_in[0];
    const int* hp  = (const int*)d_in[1];
    const int* wp  = (const int*)d_in[2];
    float* out     = (float*)d_out;

    // out_size is the number of float elements -> float4 count = /4
    const unsigned int n4 = (unsigned int)(out_size / 4);

    // Memory-bound: cap grid and grid-stride the rest (Guideline 11). n4 is a
    // safe upper bound on the per-image unit count (span <= n4).
    unsigned int blocks = (n4 + 255u) / 256u;
    if (blocks > 2048u) blocks = 2048u;
    pe_add_kernel<<<blocks, 256, 0, stream>>>(x, hp, wp, out, n4);
}

// Round 5
// 225.066 us; speedup vs baseline: 1.0692x; 1.0692x over previous
//
#include <hip/hip_runtime.h>
#include <math.h>

// out[b, l, d] = x[b, l, d] + pe[l, d]
// pe[l, 0:128]   : interleaved sin/cos of row * freq_m   (m = 0..63)
// pe[l, 128:256] : interleaved sin/cos of col * freq_m
// freq_m = exp(-m * ln(10000)/64),  l = row * w + col,  d_model = 256
//
// Structure: linear one-float4-per-thread full grid (round-0 verified layout;
// the batch-amortized 16MiB-strided variant regressed 222.6 -> 240.6 us:
// power-of-2 multi-stream striding broke streaming BW; VALU prologue was
// already hidden by TLP, so amortizing it bought nothing).
// Only change vs round-0: pow2 shift/mask fast path for the two divisions.

__global__ __launch_bounds__(256) void pe_add_kernel(
    const float* __restrict__ x,
    const int* __restrict__ hp,
    const int* __restrict__ wp,
    float* __restrict__ out,
    unsigned int n4)   // total number of float4 elements
{
    unsigned int idx = blockIdx.x * blockDim.x + threadIdx.x;
    if (idx >= n4) return;

    const unsigned int ww = (unsigned int)(*wp);
    const unsigned int hh = (unsigned int)(*hp);
    const unsigned int L  = hh * ww;

    const unsigned int j = idx & 63u;   // float4 index within the 256-wide d dim
    const unsigned int t = idx >> 6;    // b * L + l

    // wave-uniform pow2 fast path (bench: w=128, L=16384)
    unsigned int l, row, col;
    if (((ww & (ww - 1u)) | (L & (L - 1u))) == 0u) {
        const unsigned int wshift = (unsigned int)__builtin_ctz(ww);
        l   = t & (L - 1u);
        row = l >> wshift;
        col = l & (ww - 1u);
    } else {
        l   = t % L;
        row = l / ww;
        col = l - row * ww;
    }

    const unsigned int d0 = j << 2;           // starting channel (0..252, step 4)
    const unsigned int dd = d0 & 127u;        // offset within the row/col half
    const float pos = (float)((d0 < 128u) ? row : col);

    const unsigned int m0 = dd >> 1;          // frequency index of first pair
    const float cstep = 0.14391156831212787f; // ln(10000)/64
    const float f0 = __expf(-(float)m0 * cstep);
    const float f1 = __expf(-(float)(m0 + 1u) * cstep);

    float s0, c0, s1, c1;
    __sincosf(pos * f0, &s0, &c0);
    __sincosf(pos * f1, &s1, &c1);

    const float4 xv = reinterpret_cast<const float4*>(x)[idx];
    float4 ov;
    ov.x = xv.x + s0;
    ov.y = xv.y + c0;
    ov.z = xv.z + s1;
    ov.w = xv.w + c1;
    reinterpret_cast<float4*>(out)[idx] = ov;
}

extern "C" void kernel_launch(void* const* d_in, const int* in_sizes, int n_in,
                              void* d_out, int out_size, void* d_ws, size_t ws_size,
                              hipStream_t stream) {
    const float* x = (const float*)d_in[0];
    const int* hp  = (const int*)d_in[1];
    const int* wp  = (const int*)d_in[2];
    float* out     = (float*)d_out;

    // out_size is in float elements -> float4 count = /4 (round-0 verified)
    const unsigned int n4 = (unsigned int)(out_size / 4);
    const unsigned int blocks = (n4 + 255u) / 256u;
    pe_add_kernel<<<blocks, 256, 0, stream>>>(x, hp, wp, out, n4);
}